// Round 7
// baseline (343.694 us; speedup 1.0000x reference)
//
#include <hip/hip_runtime.h>
#include <math.h>

// ---------------------------------------------------------------------------
// GAT (3-layer PyG GATConv, eval) on MI355X.
//   CSR build: two-level bucket sort (k_bcount -> k_bscan -> k_bplace ->
//              k_bfinal emits rowptr + ssrc + sdst), all heavy writes coalesced.
//   per layer: k_gemm = fp16 MFMA (16x16x32_f16, fp32 acc) + fused logits;
//              k_edge = per-edge alpha = exp(leakyrelu(als[s]+ald[d])) (fp32);
//              k_agg  = pure gather+FMA segment softmax aggregation.
// R7: alpha precompute kernel; v_fma_mix_f32 inner loop; 32-bit addressing.
// ---------------------------------------------------------------------------

#define N_NODES 100000
#define NBUCK ((N_NODES + 255) / 256)   // 391 buckets of 256 nodes

typedef __attribute__((ext_vector_type(4))) _Float16 half4;
typedef __attribute__((ext_vector_type(8))) _Float16 half8;
typedef __attribute__((ext_vector_type(4))) float f32x4;

// fma_mix: alo += s * f16lo(u); ahi += s * f16hi(u)   (exact: f16 widened)
__device__ inline void fmamix2(float& alo, float& ahi, float s, unsigned u) {
    asm("v_fma_mix_f32 %0, %1, %2, %0 op_sel_hi:[0,1,0]" : "+v"(alo) : "v"(s), "v"(u));
    asm("v_fma_mix_f32 %0, %1, %2, %0 op_sel:[0,1,0] op_sel_hi:[0,1,0]" : "+v"(ahi) : "v"(s), "v"(u));
}

// ------------------------------ CSR build ----------------------------------

__global__ __launch_bounds__(256) void k_bcount(const int* __restrict__ ei, int E, int ETOT,
                                                int* __restrict__ bucketCnt) {
    __shared__ int h[NBUCK];
    for (int b = threadIdx.x; b < NBUCK; b += 256) h[b] = 0;
    __syncthreads();
    const int base = blockIdx.x * 4096;
#pragma unroll
    for (int j = 0; j < 16; ++j) {
        int idx = base + j * 256 + threadIdx.x;
        if (idx < ETOT) {
            int dst = (idx < E) ? ei[E + idx] : (idx - E);
            atomicAdd(&h[dst >> 8], 1);
        }
    }
    __syncthreads();
    for (int b = threadIdx.x; b < NBUCK; b += 256)
        if (h[b]) atomicAdd(&bucketCnt[b], h[b]);
}

__global__ __launch_bounds__(256) void k_bscan(const int* __restrict__ bucketCnt,
                                               int* __restrict__ bstart,
                                               int* __restrict__ gcur, int ETOT) {
    __shared__ int lds[512];
    const int t = threadIdx.x;
    lds[t] = (t < NBUCK) ? bucketCnt[t] : 0;
    lds[t + 256] = (t + 256 < NBUCK) ? bucketCnt[t + 256] : 0;
    __syncthreads();
    for (int d = 1; d < 512; d <<= 1) {
        int v0 = (t >= d) ? lds[t - d] : 0;
        int v1 = (t + 256 >= d) ? lds[t + 256 - d] : 0;
        __syncthreads();
        lds[t] += v0;
        lds[t + 256] += v1;
        __syncthreads();
    }
    int e0 = (t == 0) ? 0 : lds[t - 1];
    int e1 = lds[t + 255];
    if (t < NBUCK)       { bstart[t] = e0;       gcur[t] = e0; }
    if (t + 256 < NBUCK) { bstart[t + 256] = e1; gcur[t + 256] = e1; }
    if (t == 0) bstart[NBUCK] = ETOT;
}

__global__ __launch_bounds__(256) void k_bplace(const int* __restrict__ ei, int E, int ETOT,
                                                int* __restrict__ gcur, int* __restrict__ tmp) {
    __shared__ int h[NBUCK];
    __shared__ int cur[NBUCK];
    for (int b = threadIdx.x; b < NBUCK; b += 256) h[b] = 0;
    __syncthreads();
    const int base = blockIdx.x * 4096;
    int pk[16], bk[16];
#pragma unroll
    for (int j = 0; j < 16; ++j) {
        int idx = base + j * 256 + threadIdx.x;
        bk[j] = -1;
        if (idx < ETOT) {
            int s, d;
            if (idx < E) { s = ei[idx]; d = ei[E + idx]; }
            else         { s = idx - E; d = idx - E; }
            bk[j] = d >> 8;
            pk[j] = s | ((d & 255) << 17);
            atomicAdd(&h[bk[j]], 1);
        }
    }
    __syncthreads();
    for (int b = threadIdx.x; b < NBUCK; b += 256)
        cur[b] = h[b] ? atomicAdd(&gcur[b], h[b]) : 0;
    __syncthreads();
#pragma unroll
    for (int j = 0; j < 16; ++j) {
        if (bk[j] >= 0) {
            int pos = atomicAdd(&cur[bk[j]], 1);
            tmp[pos] = pk[j];
        }
    }
}

__global__ __launch_bounds__(256) void k_bfinal(const int* __restrict__ tmp,
                                                const int* __restrict__ bstart,
                                                int* __restrict__ rowptr,
                                                int* __restrict__ ssrc,
                                                int* __restrict__ sdst, int N) {
    __shared__ int cnt[256];
    __shared__ int cur[256];
    const int t = threadIdx.x;
    const int b = blockIdx.x;
    const int s0 = bstart[b], s1 = bstart[b + 1];
    cnt[t] = 0;
    __syncthreads();
    for (int e = s0 + t; e < s1; e += 256)
        atomicAdd(&cnt[tmp[e] >> 17], 1);
    __syncthreads();
    int c0 = cnt[t];
    for (int d = 1; d < 256; d <<= 1) {
        int v = (t >= d) ? cnt[t - d] : 0;
        __syncthreads();
        cnt[t] += v;
        __syncthreads();
    }
    int excl = cnt[t] - c0;
    int node = b * 256 + t;
    if (node <= N) rowptr[node] = s0 + excl;
    cur[t] = excl;
    __syncthreads();
    for (int e = s0 + t; e < s1; e += 256) {
        int p = tmp[e];
        int pos = atomicAdd(&cur[p >> 17], 1);
        ssrc[s0 + pos] = p & 0x1FFFF;
        sdst[s0 + pos] = (b << 8) | (p >> 17);
    }
}

// --------------------------- W transposes to fp16 ---------------------------
__global__ void k_wt3(const float* __restrict__ W0, const float* __restrict__ W1,
                      const float* __restrict__ W2, _Float16* __restrict__ wt0,
                      _Float16* __restrict__ wt1, _Float16* __restrict__ wt2) {
    int idx = blockIdx.x * 256 + threadIdx.x;
    if (idx < 16384) {
        int k = idx >> 7, n = idx & 127;
        wt0[n * 128 + k] = (_Float16)W0[idx];
    } else if (idx < 32768) {
        int i = idx - 16384;
        int k = i >> 7, n = i & 127;
        wt1[n * 128 + k] = (_Float16)W1[i];
    } else if (idx < 40960) {
        int i = idx - 32768;
        int k = i >> 6, n = i & 63;
        wt2[n * 128 + k] = (_Float16)W2[i];
    }
}

// ------------------------------ MFMA GEMM + logits --------------------------
template <int OUT, int H, bool INF16>
__global__ __launch_bounds__(256) void k_gemm(const void* __restrict__ Xv_,
                                              const _Float16* __restrict__ Wt,
                                              const float* __restrict__ a_src,
                                              const float* __restrict__ a_dst,
                                              _Float16* __restrict__ XP,
                                              float* __restrict__ al_s,
                                              float* __restrict__ al_d, int N) {
    constexpr int NT = OUT / 16;
    constexpr int C = OUT / H;
    constexpr int LDH = 136;
    __shared__ _Float16 As[64 * LDH];
    __shared__ _Float16 Ws[OUT * LDH];
    const int tid = threadIdx.x;
    const int row0 = blockIdx.x * 64;

    for (int c = tid; c < OUT * 16; c += 256) {
        int r = c >> 4, kc = c & 15;
        *(half8*)&Ws[r * LDH + kc * 8] = *(const half8*)(Wt + r * 128 + kc * 8);
    }
    for (int c = tid; c < 64 * 16; c += 256) {
        int r = c >> 4, kc = c & 15;
        int grow = row0 + r;
        half8 hv;
        if (grow < N) {
            if constexpr (INF16) {
                hv = *(const half8*)((const _Float16*)Xv_ + (size_t)grow * 128 + kc * 8);
            } else {
                const float4* xr = (const float4*)((const float*)Xv_ + (size_t)grow * 128 + kc * 8);
                float4 x0 = xr[0], x1 = xr[1];
                hv[0] = (_Float16)x0.x; hv[1] = (_Float16)x0.y;
                hv[2] = (_Float16)x0.z; hv[3] = (_Float16)x0.w;
                hv[4] = (_Float16)x1.x; hv[5] = (_Float16)x1.y;
                hv[6] = (_Float16)x1.z; hv[7] = (_Float16)x1.w;
            }
        } else {
#pragma unroll
            for (int j = 0; j < 8; ++j) hv[j] = (_Float16)0.f;
        }
        *(half8*)&As[r * LDH + kc * 8] = hv;
    }
    __syncthreads();

    const int w = tid >> 6;
    const int l = tid & 63;
    const int lm = l & 15;
    const int lk = l >> 4;

    f32x4 acc[NT];
#pragma unroll
    for (int nt = 0; nt < NT; ++nt) acc[nt] = {0.f, 0.f, 0.f, 0.f};

#pragma unroll
    for (int ks = 0; ks < 4; ++ks) {
        half8 av = *(const half8*)&As[(w * 16 + lm) * LDH + ks * 32 + lk * 8];
#pragma unroll
        for (int nt = 0; nt < NT; ++nt) {
            half8 bv = *(const half8*)&Ws[(nt * 16 + lm) * LDH + ks * 32 + lk * 8];
            acc[nt] = __builtin_amdgcn_mfma_f32_16x16x32_f16(av, bv, acc[nt], 0, 0, 0);
        }
    }

    float avs[NT], avd[NT];
#pragma unroll
    for (int nt = 0; nt < NT; ++nt) {
        avs[nt] = a_src[nt * 16 + lm];
        avd[nt] = a_dst[nt * 16 + lm];
    }

#pragma unroll
    for (int r = 0; r < 4; ++r) {
        int grow = row0 + w * 16 + lk * 4 + r;
        bool ok = grow < N;
#pragma unroll
        for (int nt = 0; nt < NT; ++nt)
            if (ok) XP[(size_t)grow * OUT + nt * 16 + lm] = (_Float16)acc[nt][r];

        float ps[H], pd[H];
#pragma unroll
        for (int h = 0; h < H; ++h) { ps[h] = 0.f; pd[h] = 0.f; }
#pragma unroll
        for (int nt = 0; nt < NT; ++nt) {
            int h = (nt * 16) / C;
            ps[h] += acc[nt][r] * avs[nt];
            pd[h] += acc[nt][r] * avd[nt];
        }
#pragma unroll
        for (int h = 0; h < H; ++h) {
#pragma unroll
            for (int o = 8; o >= 1; o >>= 1) {
                ps[h] += __shfl_xor(ps[h], o);
                pd[h] += __shfl_xor(pd[h], o);
            }
        }
        if (ok && lm == 0) {
#pragma unroll
            for (int h = 0; h < H; ++h) {
                al_s[(size_t)grow * H + h] = ps[h];
                al_d[(size_t)grow * H + h] = pd[h];
            }
        }
    }
}

// ------------------------------ per-edge alpha ------------------------------
// alpha[e][h] = exp(leakyrelu(al_s[src][h] + al_d[dst][h]))
template <int H>
__global__ __launch_bounds__(256) void k_edge(const int* __restrict__ ssrc,
                                              const int* __restrict__ sdst,
                                              const float* __restrict__ al_s,
                                              const float* __restrict__ al_d,
                                              float* __restrict__ alpha, int ETOT) {
    int idx = blockIdx.x * 256 + threadIdx.x;
    if (idx >= ETOT) return;
    int s = ssrc[idx], d = sdst[idx];
    if constexpr (H == 4) {
        float4 as = ((const float4*)al_s)[s];
        float4 ad = ((const float4*)al_d)[d];
        float e0 = as.x + ad.x; e0 = e0 > 0.f ? e0 : 0.2f * e0;
        float e1 = as.y + ad.y; e1 = e1 > 0.f ? e1 : 0.2f * e1;
        float e2 = as.z + ad.z; e2 = e2 > 0.f ? e2 : 0.2f * e2;
        float e3 = as.w + ad.w; e3 = e3 > 0.f ? e3 : 0.2f * e3;
        ((float4*)alpha)[idx] = make_float4(__expf(e0), __expf(e1), __expf(e2), __expf(e3));
    } else {
        float e = al_s[s] + al_d[d];
        e = e > 0.f ? e : 0.2f * e;
        alpha[idx] = __expf(e);
    }
}

// --------------------------- softmax + aggregate ----------------------------
// one wave per node; quarter-wave (16 lanes) per edge, 16-edge main trips.
// inner loop: ssrc + alpha loads, then v_fma_mix_f32 gather-accumulate.
template <int OUT, int H, bool ELU, bool OUTF16>
__global__ __launch_bounds__(256) void k_agg(const _Float16* __restrict__ xp,
                                             const float* __restrict__ alpha,
                                             const int* __restrict__ rowptr,
                                             const int* __restrict__ ssrc,
                                             const float* __restrict__ bias,
                                             void* __restrict__ out_, int N) {
    constexpr int C = OUT / H;
    constexpr int CPL = OUT / 16;  // fp16 channels per lane in a quarter (8 or 4)
    const int wid = threadIdx.x >> 6;
    const int lane = threadIdx.x & 63;
    const int qid = lane >> 4;
    const int l4 = lane & 15;
    const int node = blockIdx.x * 4 + wid;
    if (node >= N) return;
    const int rs = rowptr[node];
    const int re = rowptr[node + 1];

    const int c0 = l4 * CPL;
    const int hd = c0 / C;

    float ssum = 0.f;
    float acc[CPL];
#pragma unroll
    for (int j = 0; j < CPL; ++j) acc[j] = 0.f;

    auto edge = [&](int idx) {
        int s = ssrc[idx];
        float a = alpha[(unsigned)idx * H + hd];
        ssum += a;
        unsigned off = (unsigned)s * OUT + c0;
        if constexpr (CPL == 8) {
            uint4 u = *(const uint4*)(xp + off);
            fmamix2(acc[0], acc[1], a, u.x);
            fmamix2(acc[2], acc[3], a, u.y);
            fmamix2(acc[4], acc[5], a, u.z);
            fmamix2(acc[6], acc[7], a, u.w);
        } else {
            uint2 u = *(const uint2*)(xp + off);
            fmamix2(acc[0], acc[1], a, u.x);
            fmamix2(acc[2], acc[3], a, u.y);
        }
    };

    int i = rs;
    for (; i + 16 <= re; i += 16) {
        edge(i + qid); edge(i + qid + 4); edge(i + qid + 8); edge(i + qid + 12);
    }
    for (; i + 8 <= re; i += 8) {
        edge(i + qid); edge(i + qid + 4);
    }
    for (; i + qid < re; i += 4) {
        edge(i + qid);
    }

    ssum += __shfl_xor(ssum, 16);
    ssum += __shfl_xor(ssum, 32);
#pragma unroll
    for (int j = 0; j < CPL; ++j) {
        acc[j] += __shfl_xor(acc[j], 16);
        acc[j] += __shfl_xor(acc[j], 32);
    }

    if (qid == 0) {
        float inv = 1.f / (ssum + 1e-16f);
        float o[CPL];
#pragma unroll
        for (int j = 0; j < CPL; ++j) {
            o[j] = acc[j] * inv + bias[c0 + j];
            if constexpr (ELU) o[j] = o[j] > 0.f ? o[j] : (__expf(o[j]) - 1.f);
        }
        if constexpr (OUTF16) {
            _Float16* op = (_Float16*)out_ + (size_t)node * OUT + c0;
            if constexpr (CPL == 8) {
                half8 hv;
#pragma unroll
                for (int j = 0; j < 8; ++j) hv[j] = (_Float16)o[j];
                *(half8*)op = hv;
            } else {
                half4 hv;
#pragma unroll
                for (int j = 0; j < 4; ++j) hv[j] = (_Float16)o[j];
                *(half4*)op = hv;
            }
        } else {
            float* op = (float*)out_ + (size_t)node * OUT + c0;
            if constexpr (CPL == 8) {
                *(float4*)op = make_float4(o[0], o[1], o[2], o[3]);
                *(float4*)(op + 4) = make_float4(o[4], o[5], o[6], o[7]);
            } else {
                *(float4*)op = make_float4(o[0], o[1], o[2], o[3]);
            }
        }
    }
}

// ------------------------------ launch --------------------------------------

extern "C" void kernel_launch(void* const* d_in, const int* in_sizes, int n_in,
                              void* d_out, int out_size, void* d_ws, size_t ws_size,
                              hipStream_t stream) {
    const int N = N_NODES;
    const float* x     = (const float*)d_in[0];
    const int*   ei    = (const int*)d_in[1];
    const float* W0    = (const float*)d_in[2];
    const float* as0   = (const float*)d_in[3];
    const float* ad0   = (const float*)d_in[4];
    const float* b0    = (const float*)d_in[5];
    const float* W1    = (const float*)d_in[6];
    const float* as1   = (const float*)d_in[7];
    const float* ad1   = (const float*)d_in[8];
    const float* b1    = (const float*)d_in[9];
    const float* W2    = (const float*)d_in[10];
    const float* as2   = (const float*)d_in[11];
    const float* ad2   = (const float*)d_in[12];
    const float* b2    = (const float*)d_in[13];
    float* out = (float*)d_out;

    const int E = in_sizes[1] / 2;
    const int ETOT = E + N;

    char* p = (char*)d_ws;
    auto alloc = [&](size_t bytes) {
        void* r = (void*)p;
        p += (bytes + 255) & ~(size_t)255;
        return r;
    };
    _Float16* xp    = (_Float16*)alloc((size_t)N * 128 * 2);
    _Float16* hbuf  = (_Float16*)alloc((size_t)N * 128 * 2);
    float* als      = (float*)alloc((size_t)N * 4 * 4);
    float* ald      = (float*)alloc((size_t)N * 4 * 4);
    int*   rowptr   = (int*)alloc((size_t)(N + 1) * 4);
    int*   ssrc     = (int*)alloc((size_t)ETOT * 4);
    int*   sdst     = (int*)alloc((size_t)ETOT * 4);
    float* alpha    = (float*)alloc((size_t)ETOT * 4 * 4);  // also aliased as tmp
    int*   tmp      = (int*)alpha;                          // dead before k_edge
    int*   bucketCnt= (int*)alloc((size_t)NBUCK * 4);
    int*   bstart   = (int*)alloc((size_t)(NBUCK + 1) * 4);
    int*   gcur     = (int*)alloc((size_t)NBUCK * 4);
    _Float16* wt0   = (_Float16*)alloc((size_t)128 * 128 * 2);
    _Float16* wt1   = (_Float16*)alloc((size_t)128 * 128 * 2);
    _Float16* wt2   = (_Float16*)alloc((size_t)128 * 64 * 2);

    // ---- W transposes (one fused launch) ----
    k_wt3<<<160, 256, 0, stream>>>(W0, W1, W2, wt0, wt1, wt2);

    // ---- CSR build (bucket sort) ----
    const int PB = (ETOT + 4095) / 4096;
    hipMemsetAsync(bucketCnt, 0, (size_t)NBUCK * 4, stream);
    k_bcount<<<PB, 256, 0, stream>>>(ei, E, ETOT, bucketCnt);
    k_bscan<<<1, 256, 0, stream>>>(bucketCnt, bstart, gcur, ETOT);
    k_bplace<<<PB, 256, 0, stream>>>(ei, E, ETOT, gcur, tmp);
    k_bfinal<<<NBUCK, 256, 0, stream>>>(tmp, bstart, rowptr, ssrc, sdst, N);

    const int gGemm = (N + 63) / 64;
    const int gAgg  = (N + 3) / 4;
    const int gEdge = (ETOT + 255) / 256;

    // ---- layer 0: 128 -> 4x32, ELU ----
    k_gemm<128, 4, false><<<gGemm, 256, 0, stream>>>(x, wt0, as0, ad0, xp, als, ald, N);
    k_edge<4><<<gEdge, 256, 0, stream>>>(ssrc, sdst, als, ald, alpha, ETOT);
    k_agg<128, 4, true, true><<<gAgg, 256, 0, stream>>>(xp, alpha, rowptr, ssrc, b0, hbuf, N);

    // ---- layer 1: 128 -> 4x32, ELU ----
    k_gemm<128, 4, true><<<gGemm, 256, 0, stream>>>(hbuf, wt1, as1, ad1, xp, als, ald, N);
    k_edge<4><<<gEdge, 256, 0, stream>>>(ssrc, sdst, als, ald, alpha, ETOT);
    k_agg<128, 4, true, true><<<gAgg, 256, 0, stream>>>(xp, alpha, rowptr, ssrc, b1, hbuf, N);

    // ---- layer 2: 128 -> 1x64, no ELU ----
    k_gemm<64, 1, true><<<gGemm, 256, 0, stream>>>(hbuf, wt2, as2, ad2, xp, als, ald, N);
    k_edge<1><<<gEdge, 256, 0, stream>>>(ssrc, sdst, als, ald, alpha, ETOT);
    k_agg<64, 1, false, false><<<gAgg, 256, 0, stream>>>(xp, alpha, rowptr, ssrc, b2, out, N);
}

// Round 9
// 324.870 us; speedup vs baseline: 1.0579x; 1.0579x over previous
//
#include <hip/hip_runtime.h>
#include <math.h>

// ---------------------------------------------------------------------------
// GAT (3-layer PyG GATConv, eval) on MI355X.
//   CSR build: two-level bucket sort (k_bcount -> k_bscan -> k_bplace ->
//              k_bfinal), all heavy writes coalesced.
//   per layer: k_gemm = fp16 MFMA (16x16x32_f16, fp32 acc) + fused logits;
//              k_agg  = single-pass segment softmax aggregation with inline
//                       alpha (per-lane head) and v_fma_mix_f32 gather-FMA.
// R9: R8 with the k_wt3 grid off-by-one fixed (zeroing range covered exactly;
//     R8 left buckets 256..390 poisoned -> OOB writes in k_bplace -> fault).
// ---------------------------------------------------------------------------

#define N_NODES 100000
#define NBUCK ((N_NODES + 255) / 256)   // 391 buckets of 256 nodes
#define WT_ELEMS (16384 + 16384 + 8192) // wt0 + wt1 + wt2 elements
#define WT_TOT (WT_ELEMS + NBUCK)       // + bucketCnt zeroing

typedef __attribute__((ext_vector_type(4))) _Float16 half4;
typedef __attribute__((ext_vector_type(8))) _Float16 half8;
typedef __attribute__((ext_vector_type(4))) float f32x4;

// fma_mix: alo += s * f16lo(u); ahi += s * f16hi(u)   (exact: f16 widened)
__device__ inline void fmamix2(float& alo, float& ahi, float s, unsigned u) {
    asm("v_fma_mix_f32 %0, %1, %2, %0 op_sel_hi:[0,1,0]" : "+v"(alo) : "v"(s), "v"(u));
    asm("v_fma_mix_f32 %0, %1, %2, %0 op_sel:[0,1,0] op_sel_hi:[0,1,0]" : "+v"(ahi) : "v"(s), "v"(u));
}

// ------------------------------ CSR build ----------------------------------

__global__ __launch_bounds__(256) void k_bcount(const int* __restrict__ ei, int E, int ETOT,
                                                int* __restrict__ bucketCnt) {
    __shared__ int h[NBUCK];
    for (int b = threadIdx.x; b < NBUCK; b += 256) h[b] = 0;
    __syncthreads();
    const int base = blockIdx.x * 4096;
#pragma unroll
    for (int j = 0; j < 16; ++j) {
        int idx = base + j * 256 + threadIdx.x;
        if (idx < ETOT) {
            int dst = (idx < E) ? ei[E + idx] : (idx - E);
            atomicAdd(&h[dst >> 8], 1);
        }
    }
    __syncthreads();
    for (int b = threadIdx.x; b < NBUCK; b += 256)
        if (h[b]) atomicAdd(&bucketCnt[b], h[b]);
}

__global__ __launch_bounds__(256) void k_bscan(const int* __restrict__ bucketCnt,
                                               int* __restrict__ bstart,
                                               int* __restrict__ gcur, int ETOT) {
    __shared__ int lds[512];
    const int t = threadIdx.x;
    lds[t] = (t < NBUCK) ? bucketCnt[t] : 0;
    lds[t + 256] = (t + 256 < NBUCK) ? bucketCnt[t + 256] : 0;
    __syncthreads();
    for (int d = 1; d < 512; d <<= 1) {
        int v0 = (t >= d) ? lds[t - d] : 0;
        int v1 = (t + 256 >= d) ? lds[t + 256 - d] : 0;
        __syncthreads();
        lds[t] += v0;
        lds[t + 256] += v1;
        __syncthreads();
    }
    int e0 = (t == 0) ? 0 : lds[t - 1];
    int e1 = lds[t + 255];
    if (t < NBUCK)       { bstart[t] = e0;       gcur[t] = e0; }
    if (t + 256 < NBUCK) { bstart[t + 256] = e1; gcur[t + 256] = e1; }
    if (t == 0) bstart[NBUCK] = ETOT;
}

__global__ __launch_bounds__(256) void k_bplace(const int* __restrict__ ei, int E, int ETOT,
                                                int* __restrict__ gcur, int* __restrict__ tmp) {
    __shared__ int h[NBUCK];
    __shared__ int cur[NBUCK];
    for (int b = threadIdx.x; b < NBUCK; b += 256) h[b] = 0;
    __syncthreads();
    const int base = blockIdx.x * 4096;
    int pk[16], bk[16];
#pragma unroll
    for (int j = 0; j < 16; ++j) {
        int idx = base + j * 256 + threadIdx.x;
        bk[j] = -1;
        if (idx < ETOT) {
            int s, d;
            if (idx < E) { s = ei[idx]; d = ei[E + idx]; }
            else         { s = idx - E; d = idx - E; }
            bk[j] = d >> 8;
            pk[j] = s | ((d & 255) << 17);
            atomicAdd(&h[bk[j]], 1);
        }
    }
    __syncthreads();
    for (int b = threadIdx.x; b < NBUCK; b += 256)
        cur[b] = h[b] ? atomicAdd(&gcur[b], h[b]) : 0;
    __syncthreads();
#pragma unroll
    for (int j = 0; j < 16; ++j) {
        if (bk[j] >= 0) {
            int pos = atomicAdd(&cur[bk[j]], 1);
            tmp[pos] = pk[j];
        }
    }
}

__global__ __launch_bounds__(256) void k_bfinal(const int* __restrict__ tmp,
                                                const int* __restrict__ bstart,
                                                int* __restrict__ rowptr,
                                                int* __restrict__ ssrc, int N) {
    __shared__ int cnt[256];
    __shared__ int cur[256];
    const int t = threadIdx.x;
    const int b = blockIdx.x;
    const int s0 = bstart[b], s1 = bstart[b + 1];
    cnt[t] = 0;
    __syncthreads();
    for (int e = s0 + t; e < s1; e += 256)
        atomicAdd(&cnt[tmp[e] >> 17], 1);
    __syncthreads();
    int c0 = cnt[t];
    for (int d = 1; d < 256; d <<= 1) {
        int v = (t >= d) ? cnt[t - d] : 0;
        __syncthreads();
        cnt[t] += v;
        __syncthreads();
    }
    int excl = cnt[t] - c0;
    int node = b * 256 + t;
    if (node <= N) rowptr[node] = s0 + excl;
    cur[t] = excl;
    __syncthreads();
    for (int e = s0 + t; e < s1; e += 256) {
        int p = tmp[e];
        int pos = atomicAdd(&cur[p >> 17], 1);
        ssrc[s0 + pos] = p & 0x1FFFF;
    }
}

// ------------------- W transposes to fp16 (+ bucketCnt zero) ----------------
__global__ void k_wt3(const float* __restrict__ W0, const float* __restrict__ W1,
                      const float* __restrict__ W2, _Float16* __restrict__ wt0,
                      _Float16* __restrict__ wt1, _Float16* __restrict__ wt2,
                      int* __restrict__ bucketCnt) {
    int idx = blockIdx.x * 256 + threadIdx.x;
    if (idx < 16384) {
        int k = idx >> 7, n = idx & 127;
        wt0[n * 128 + k] = (_Float16)W0[idx];
    } else if (idx < 32768) {
        int i = idx - 16384;
        int k = i >> 7, n = i & 127;
        wt1[n * 128 + k] = (_Float16)W1[i];
    } else if (idx < WT_ELEMS) {
        int i = idx - 32768;
        int k = i >> 6, n = i & 63;
        wt2[n * 128 + k] = (_Float16)W2[i];
    } else if (idx < WT_TOT) {
        bucketCnt[idx - WT_ELEMS] = 0;
    }
}

// ------------------------------ MFMA GEMM + logits --------------------------
template <int OUT, int H, bool INF16>
__global__ __launch_bounds__(256) void k_gemm(const void* __restrict__ Xv_,
                                              const _Float16* __restrict__ Wt,
                                              const float* __restrict__ a_src,
                                              const float* __restrict__ a_dst,
                                              _Float16* __restrict__ XP,
                                              float* __restrict__ al_s,
                                              float* __restrict__ al_d, int N) {
    constexpr int NT = OUT / 16;
    constexpr int C = OUT / H;
    constexpr int LDH = 136;
    __shared__ _Float16 As[64 * LDH];
    __shared__ _Float16 Ws[OUT * LDH];
    const int tid = threadIdx.x;
    const int row0 = blockIdx.x * 64;

    for (int c = tid; c < OUT * 16; c += 256) {
        int r = c >> 4, kc = c & 15;
        *(half8*)&Ws[r * LDH + kc * 8] = *(const half8*)(Wt + r * 128 + kc * 8);
    }
    for (int c = tid; c < 64 * 16; c += 256) {
        int r = c >> 4, kc = c & 15;
        int grow = row0 + r;
        half8 hv;
        if (grow < N) {
            if constexpr (INF16) {
                hv = *(const half8*)((const _Float16*)Xv_ + (size_t)grow * 128 + kc * 8);
            } else {
                const float4* xr = (const float4*)((const float*)Xv_ + (size_t)grow * 128 + kc * 8);
                float4 x0 = xr[0], x1 = xr[1];
                hv[0] = (_Float16)x0.x; hv[1] = (_Float16)x0.y;
                hv[2] = (_Float16)x0.z; hv[3] = (_Float16)x0.w;
                hv[4] = (_Float16)x1.x; hv[5] = (_Float16)x1.y;
                hv[6] = (_Float16)x1.z; hv[7] = (_Float16)x1.w;
            }
        } else {
#pragma unroll
            for (int j = 0; j < 8; ++j) hv[j] = (_Float16)0.f;
        }
        *(half8*)&As[r * LDH + kc * 8] = hv;
    }
    __syncthreads();

    const int w = tid >> 6;
    const int l = tid & 63;
    const int lm = l & 15;
    const int lk = l >> 4;

    f32x4 acc[NT];
#pragma unroll
    for (int nt = 0; nt < NT; ++nt) acc[nt] = {0.f, 0.f, 0.f, 0.f};

#pragma unroll
    for (int ks = 0; ks < 4; ++ks) {
        half8 av = *(const half8*)&As[(w * 16 + lm) * LDH + ks * 32 + lk * 8];
#pragma unroll
        for (int nt = 0; nt < NT; ++nt) {
            half8 bv = *(const half8*)&Ws[(nt * 16 + lm) * LDH + ks * 32 + lk * 8];
            acc[nt] = __builtin_amdgcn_mfma_f32_16x16x32_f16(av, bv, acc[nt], 0, 0, 0);
        }
    }

    float avs[NT], avd[NT];
#pragma unroll
    for (int nt = 0; nt < NT; ++nt) {
        avs[nt] = a_src[nt * 16 + lm];
        avd[nt] = a_dst[nt * 16 + lm];
    }

#pragma unroll
    for (int r = 0; r < 4; ++r) {
        int grow = row0 + w * 16 + lk * 4 + r;
        bool ok = grow < N;
#pragma unroll
        for (int nt = 0; nt < NT; ++nt)
            if (ok) XP[(size_t)grow * OUT + nt * 16 + lm] = (_Float16)acc[nt][r];

        float ps[H], pd[H];
#pragma unroll
        for (int h = 0; h < H; ++h) { ps[h] = 0.f; pd[h] = 0.f; }
#pragma unroll
        for (int nt = 0; nt < NT; ++nt) {
            int h = (nt * 16) / C;
            ps[h] += acc[nt][r] * avs[nt];
            pd[h] += acc[nt][r] * avd[nt];
        }
#pragma unroll
        for (int h = 0; h < H; ++h) {
#pragma unroll
            for (int o = 8; o >= 1; o >>= 1) {
                ps[h] += __shfl_xor(ps[h], o);
                pd[h] += __shfl_xor(pd[h], o);
            }
        }
        if (ok && lm == 0) {
#pragma unroll
            for (int h = 0; h < H; ++h) {
                al_s[(size_t)grow * H + h] = ps[h];
                al_d[(size_t)grow * H + h] = pd[h];
            }
        }
    }
}

// --------------------------- softmax + aggregate ----------------------------
// one wave per node; quarter-wave (16 lanes) per edge, 16-edge main trips.
// inline per-lane alpha (head hd) + v_fma_mix_f32 gather-accumulate.
template <int OUT, int H, bool ELU, bool OUTF16>
__global__ __launch_bounds__(256) void k_agg(const _Float16* __restrict__ xp,
                                             const float* __restrict__ al_s,
                                             const float* __restrict__ al_d,
                                             const int* __restrict__ rowptr,
                                             const int* __restrict__ ssrc,
                                             const float* __restrict__ bias,
                                             void* __restrict__ out_, int N) {
    constexpr int C = OUT / H;
    constexpr int CPL = OUT / 16;  // fp16 channels per lane in a quarter (8 or 4)
    const int wid = threadIdx.x >> 6;
    const int lane = threadIdx.x & 63;
    const int qid = lane >> 4;
    const int l4 = lane & 15;
    const int node = blockIdx.x * 4 + wid;
    if (node >= N) return;
    const int rs = rowptr[node];
    const int re = rowptr[node + 1];

    const int c0 = l4 * CPL;
    const int hd = c0 / C;
    const float adh = al_d[(unsigned)node * H + hd];

    float ssum = 0.f;
    float acc[CPL];
#pragma unroll
    for (int j = 0; j < CPL; ++j) acc[j] = 0.f;

    auto edge = [&](int idx) {
        int s = ssrc[idx];
        float e = al_s[(unsigned)s * H + hd] + adh;
        e = e > 0.f ? e : 0.2f * e;
        float a = __expf(e);
        ssum += a;
        unsigned off = (unsigned)s * OUT + c0;
        if constexpr (CPL == 8) {
            uint4 u = *(const uint4*)(xp + off);
            fmamix2(acc[0], acc[1], a, u.x);
            fmamix2(acc[2], acc[3], a, u.y);
            fmamix2(acc[4], acc[5], a, u.z);
            fmamix2(acc[6], acc[7], a, u.w);
        } else {
            uint2 u = *(const uint2*)(xp + off);
            fmamix2(acc[0], acc[1], a, u.x);
            fmamix2(acc[2], acc[3], a, u.y);
        }
    };

    int i = rs;
    for (; i + 16 <= re; i += 16) {
        edge(i + qid); edge(i + qid + 4); edge(i + qid + 8); edge(i + qid + 12);
    }
    for (; i + 8 <= re; i += 8) {
        edge(i + qid); edge(i + qid + 4);
    }
    for (; i + qid < re; i += 4) {
        edge(i + qid);
    }

    ssum += __shfl_xor(ssum, 16);
    ssum += __shfl_xor(ssum, 32);
#pragma unroll
    for (int j = 0; j < CPL; ++j) {
        acc[j] += __shfl_xor(acc[j], 16);
        acc[j] += __shfl_xor(acc[j], 32);
    }

    if (qid == 0) {
        float inv = 1.f / (ssum + 1e-16f);
        float o[CPL];
#pragma unroll
        for (int j = 0; j < CPL; ++j) {
            o[j] = acc[j] * inv + bias[c0 + j];
            if constexpr (ELU) o[j] = o[j] > 0.f ? o[j] : (__expf(o[j]) - 1.f);
        }
        if constexpr (OUTF16) {
            _Float16* op = (_Float16*)out_ + (size_t)node * OUT + c0;
            if constexpr (CPL == 8) {
                half8 hv;
#pragma unroll
                for (int j = 0; j < 8; ++j) hv[j] = (_Float16)o[j];
                *(half8*)op = hv;
            } else {
                half4 hv;
#pragma unroll
                for (int j = 0; j < 4; ++j) hv[j] = (_Float16)o[j];
                *(half4*)op = hv;
            }
        } else {
            float* op = (float*)out_ + (size_t)node * OUT + c0;
            if constexpr (CPL == 8) {
                *(float4*)op = make_float4(o[0], o[1], o[2], o[3]);
                *(float4*)(op + 4) = make_float4(o[4], o[5], o[6], o[7]);
            } else {
                *(float4*)op = make_float4(o[0], o[1], o[2], o[3]);
            }
        }
    }
}

// ------------------------------ launch --------------------------------------

extern "C" void kernel_launch(void* const* d_in, const int* in_sizes, int n_in,
                              void* d_out, int out_size, void* d_ws, size_t ws_size,
                              hipStream_t stream) {
    const int N = N_NODES;
    const float* x     = (const float*)d_in[0];
    const int*   ei    = (const int*)d_in[1];
    const float* W0    = (const float*)d_in[2];
    const float* as0   = (const float*)d_in[3];
    const float* ad0   = (const float*)d_in[4];
    const float* b0    = (const float*)d_in[5];
    const float* W1    = (const float*)d_in[6];
    const float* as1   = (const float*)d_in[7];
    const float* ad1   = (const float*)d_in[8];
    const float* b1    = (const float*)d_in[9];
    const float* W2    = (const float*)d_in[10];
    const float* as2   = (const float*)d_in[11];
    const float* ad2   = (const float*)d_in[12];
    const float* b2    = (const float*)d_in[13];
    float* out = (float*)d_out;

    const int E = in_sizes[1] / 2;
    const int ETOT = E + N;

    char* p = (char*)d_ws;
    auto alloc = [&](size_t bytes) {
        void* r = (void*)p;
        p += (bytes + 255) & ~(size_t)255;
        return r;
    };
    _Float16* xp    = (_Float16*)alloc((size_t)N * 128 * 2);
    _Float16* hbuf  = (_Float16*)alloc((size_t)N * 128 * 2);
    float* als      = (float*)alloc((size_t)N * 4 * 4);
    float* ald      = (float*)alloc((size_t)N * 4 * 4);
    int*   rowptr   = (int*)alloc((size_t)(N + 1) * 4);
    int*   ssrc     = (int*)alloc((size_t)ETOT * 4);
    int*   tmp      = (int*)alloc((size_t)ETOT * 4);
    int*   bucketCnt= (int*)alloc((size_t)NBUCK * 4);
    int*   bstart   = (int*)alloc((size_t)(NBUCK + 1) * 4);
    int*   gcur     = (int*)alloc((size_t)NBUCK * 4);
    _Float16* wt0   = (_Float16*)alloc((size_t)128 * 128 * 2);
    _Float16* wt1   = (_Float16*)alloc((size_t)128 * 128 * 2);
    _Float16* wt2   = (_Float16*)alloc((size_t)128 * 64 * 2);

    // ---- W transposes + bucketCnt zeroing (grid sized to cover WT_TOT) ----
    k_wt3<<<(WT_TOT + 255) / 256, 256, 0, stream>>>(W0, W1, W2, wt0, wt1, wt2, bucketCnt);

    // ---- CSR build (bucket sort) ----
    const int PB = (ETOT + 4095) / 4096;
    k_bcount<<<PB, 256, 0, stream>>>(ei, E, ETOT, bucketCnt);
    k_bscan<<<1, 256, 0, stream>>>(bucketCnt, bstart, gcur, ETOT);
    k_bplace<<<PB, 256, 0, stream>>>(ei, E, ETOT, gcur, tmp);
    k_bfinal<<<NBUCK, 256, 0, stream>>>(tmp, bstart, rowptr, ssrc, N);

    const int gGemm = (N + 63) / 64;
    const int gAgg  = (N + 3) / 4;

    // ---- layer 0: 128 -> 4x32, ELU ----
    k_gemm<128, 4, false><<<gGemm, 256, 0, stream>>>(x, wt0, as0, ad0, xp, als, ald, N);
    k_agg<128, 4, true, true><<<gAgg, 256, 0, stream>>>(xp, als, ald, rowptr, ssrc, b0, hbuf, N);

    // ---- layer 1: 128 -> 4x32, ELU ----
    k_gemm<128, 4, true><<<gGemm, 256, 0, stream>>>(hbuf, wt1, as1, ad1, xp, als, ald, N);
    k_agg<128, 4, true, true><<<gAgg, 256, 0, stream>>>(xp, als, ald, rowptr, ssrc, b1, hbuf, N);

    // ---- layer 2: 128 -> 1x64, no ELU ----
    k_gemm<64, 1, true><<<gGemm, 256, 0, stream>>>(hbuf, wt2, as2, ad2, xp, als, ald, N);
    k_agg<64, 1, false, false><<<gAgg, 256, 0, stream>>>(xp, als, ald, rowptr, ssrc, b2, out, N);
}